// Round 1
// baseline (599.087 us; speedup 1.0000x reference)
//
#include <hip/hip_runtime.h>

// Koopman bilinear rollout: preds[b,t,d] = (z0 @ Kd^{t+1})[b,d]
// D=B=256, T=512. Kd via Neumann series (||0.5*dt*K|| ~ 0.01).
// Parallel-in-time: powers M_j = Kd^j (j=1..J, log-depth), checkpoints
// Z_i = z0*Kd^{iJ} (sequential chain, written to final out slots),
// fill t=iJ+j-1 with one big batched-GEMM launch.

#define DD 256
#define TT 512
#define MATF (DD * DD)  // 65536 floats per 256x256 matrix

// A = 0.5*exp(log_dt)*K ; X = I + A  (Horner seed)
__global__ void prep_kernel(const float* __restrict__ K,
                            const float* __restrict__ log_dt,
                            float* __restrict__ A,
                            float* __restrict__ X) {
    int idx = blockIdx.x * blockDim.x + threadIdx.x;
    float c = 0.5f * expf(log_dt[0]);
    float a = c * K[idx];
    A[idx] = a;
    int r = idx >> 8, cc = idx & 255;
    X[idx] = a + (r == cc ? 1.0f : 0.0f);
}

// One 64x64 output tile of a 256x256x256 f32 GEMM.
// epi: 0 -> C=acc ; 1 -> C=acc+I ; 2 -> C=2*acc+I
__device__ __forceinline__ void gemm_tile(const float* __restrict__ Ab,
                                          const float* __restrict__ Bb,
                                          float* __restrict__ Cb,
                                          int lda, int ldb, int ldc, int epi) {
    // +4 pad keeps rows 16B-aligned for ds_read_b128 and breaks conflicts
    __shared__ __align__(16) float As[16][68];
    __shared__ __align__(16) float Bs[16][68];
    const int tid = threadIdx.x;            // 256 threads
    const int tx = tid & 15, ty = tid >> 4;
    const int rowBase = blockIdx.y * 64, colBase = blockIdx.x * 64;

    float acc[4][4] = {{0.0f}};

    const int a_m = tid >> 2;               // 0..63 (tile row)
    const int a_k = (tid & 3) << 2;         // 0,4,8,12 (k within BK)
    const int b_k = tid >> 4;               // 0..15
    const int b_n = (tid & 15) << 2;        // 0..60

    for (int k0 = 0; k0 < DD; k0 += 16) {
        float4 av = *(const float4*)(Ab + (long long)(rowBase + a_m) * lda + (k0 + a_k));
        As[a_k + 0][a_m] = av.x;
        As[a_k + 1][a_m] = av.y;
        As[a_k + 2][a_m] = av.z;
        As[a_k + 3][a_m] = av.w;
        *(float4*)(&Bs[b_k][b_n]) =
            *(const float4*)(Bb + (long long)(k0 + b_k) * ldb + (colBase + b_n));
        __syncthreads();
#pragma unroll
        for (int kk = 0; kk < 16; ++kk) {
            float a4[4], b4[4];
            *(float4*)a4 = *(const float4*)(&As[kk][ty << 2]);
            *(float4*)b4 = *(const float4*)(&Bs[kk][tx << 2]);
#pragma unroll
            for (int i = 0; i < 4; ++i)
#pragma unroll
                for (int j = 0; j < 4; ++j)
                    acc[i][j] += a4[i] * b4[j];
        }
        __syncthreads();
    }

    const int c0 = colBase + (tx << 2);
#pragma unroll
    for (int i = 0; i < 4; ++i) {
        int r = rowBase + (ty << 2) + i;
        float4 v;
        float* vp = (float*)&v;
#pragma unroll
        for (int j = 0; j < 4; ++j) {
            float x = acc[i][j];
            if (epi == 1) x += (r == c0 + j) ? 1.0f : 0.0f;
            else if (epi == 2) x = 2.0f * x + ((r == c0 + j) ? 1.0f : 0.0f);
            vp[j] = x;
        }
        *(float4*)(Cb + (long long)r * ldc + c0) = v;
    }
}

// Batched 256x256x256 GEMM; batch via blockIdx.z with element strides.
__global__ void gemm256_kernel(const float* __restrict__ A, const float* __restrict__ Bm,
                               float* __restrict__ C,
                               int lda, int ldb, int ldc,
                               long long sA, long long sB, long long sC, int epi) {
    gemm_tile(A + blockIdx.z * sA, Bm + blockIdx.z * sB, C + blockIdx.z * sC,
              lda, ldb, ldc, epi);
}

// Fill pass: out[:, i*J+j-1, :] = Z_i @ M_j  for j=1..J-1 (checkpoints already written)
__global__ void stage3_kernel(const float* __restrict__ z0, const float* __restrict__ Mtab,
                              float* __restrict__ out, int J) {
    int bz = blockIdx.z;
    int i = bz / (J - 1);
    int j = bz % (J - 1) + 1;
    const float* Ab;
    int lda;
    if (i == 0) { Ab = z0; lda = DD; }
    else { Ab = out + (long long)(i * J - 1) * DD; lda = TT * DD; }
    const float* Bb = Mtab + (long long)(j - 1) * MATF;
    float* Cb = out + (long long)(i * J + j - 1) * DD;
    gemm_tile(Ab, Bb, Cb, lda, DD, TT * DD, 0);
}

extern "C" void kernel_launch(void* const* d_in, const int* in_sizes, int n_in,
                              void* d_out, int out_size, void* d_ws, size_t ws_size,
                              hipStream_t stream) {
    const float* z0 = (const float*)d_in[0];
    const float* Kmat = (const float*)d_in[1];
    const float* log_dt = (const float*)d_in[2];
    float* out = (float*)d_out;
    float* ws = (float*)d_ws;

    // ws layout: A | Xa | Xb | M_1..M_J   -> (3+J)*256KB
    int J = 32;
    while (J > 4 && (size_t)(3 + J) * MATF * sizeof(float) > ws_size) J >>= 1;

    float* Amat = ws;
    float* Xa = ws + MATF;
    float* Xb = ws + 2 * (long long)MATF;
    float* Mtab = ws + 3 * (long long)MATF;

    prep_kernel<<<MATF / 256, 256, 0, stream>>>(Kmat, log_dt, Amat, Xa);

    dim3 blk(256);
    dim3 g1(4, 4, 1);

    // Horner/Neumann: X <- I + A@X (4x), then Kd = I + 2*A@X  => I+2A+...+2A^6
    float* Xin = Xa;
    float* Xout = Xb;
    for (int it = 0; it < 4; ++it) {
        gemm256_kernel<<<g1, blk, 0, stream>>>(Amat, Xin, Xout, DD, DD, DD, 0, 0, 0, 1);
        float* t = Xin; Xin = Xout; Xout = t;
    }
    gemm256_kernel<<<g1, blk, 0, stream>>>(Amat, Xin, Mtab, DD, DD, DD, 0, 0, 0, 2);

    // Powers, log-depth: M_{p+1..2p} = M_{1..p} @ M_p
    for (int p = 1; p < J; p <<= 1) {
        gemm256_kernel<<<dim3(4, 4, p), blk, 0, stream>>>(
            Mtab, Mtab + (long long)(p - 1) * MATF, Mtab + (long long)p * MATF,
            DD, DD, DD, MATF, 0, MATF, 0);
    }

    // Checkpoint chain: Z_i = Z_{i-1} @ M_J, written straight to out[:, i*J-1, :]
    const float* W = Mtab + (long long)(J - 1) * MATF;
    const int nChain = TT / J;
    for (int i = 1; i <= nChain; ++i) {
        const float* Ain = (i == 1) ? z0 : out + (long long)((i - 1) * J - 1) * DD;
        int lda = (i == 1) ? DD : TT * DD;
        gemm256_kernel<<<g1, blk, 0, stream>>>(Ain, W, out + (long long)(i * J - 1) * DD,
                                               lda, DD, TT * DD, 0, 0, 0, 0);
    }

    // Parallel fill of all non-checkpoint timesteps: 512-J/J... (nChain*(J-1) batches)
    const int nb = nChain * (J - 1);
    stage3_kernel<<<dim3(4, 4, nb), blk, 0, stream>>>(z0, Mtab, out, J);
}

// Round 2
// 249.966 us; speedup vs baseline: 2.3967x; 2.3967x over previous
//
#include <hip/hip_runtime.h>

// Koopman bilinear rollout: preds[b,t,d] = (z0 @ Kd^{t+1})[b,d], D=B=256, T=512.
// Kd = (I-A)^-1(I+A), A=0.5*dt*K, ||A||~0.01 -> Neumann/Horner series.
// Parallel-in-time: M_j=Kd^j (j=1..32, log-depth), W_i=Kd^{32i} (i=1..16,
// log-depth), checkpoints Z_i=z0@W_i in ONE batched f32 launch, fill of the
// remaining 496 timesteps in ONE batched bf16-MFMA launch.

#define DD 256
#define TT 512
#define MATF (DD * DD)

typedef __attribute__((ext_vector_type(8))) short bf16x8;
typedef __attribute__((ext_vector_type(4))) float f32x4;

static __device__ __forceinline__ unsigned short f2bf(float f) {
    unsigned int u = __float_as_uint(f);
    u += 0x7fffu + ((u >> 16) & 1u);
    return (unsigned short)(u >> 16);
}

// A = 0.5*exp(log_dt)*K ; X = I + A ; optional bf16 copy of z0
__global__ void prep_kernel(const float* __restrict__ K,
                            const float* __restrict__ log_dt,
                            const float* __restrict__ z0,
                            float* __restrict__ A,
                            float* __restrict__ X,
                            unsigned short* __restrict__ Zb0) {
    int idx = blockIdx.x * blockDim.x + threadIdx.x;
    float c = 0.5f * expf(log_dt[0]);
    float a = c * K[idx];
    A[idx] = a;
    int r = idx >> 8, cc = idx & 255;
    X[idx] = a + (r == cc ? 1.0f : 0.0f);
    if (Zb0) Zb0[idx] = f2bf(z0[idx]);
}

__global__ void copyw_kernel(const float* __restrict__ src, float* __restrict__ dst) {
    int idx = blockIdx.x * blockDim.x + threadIdx.x;
    ((float4*)dst)[idx] = ((const float4*)src)[idx];
}

// MTb_j[c][k] = bf16(M_j[k][c])  (transpose+convert, 32x32 LDS tiles)
__global__ void mtrans_kernel(const float* __restrict__ Mtab,
                              unsigned short* __restrict__ MTb) {
    __shared__ float tle[32][33];
    int j = blockIdx.z;
    const float* M = Mtab + (size_t)j * MATF;
    unsigned short* MT = MTb + (size_t)j * MATF;
    int k0 = blockIdx.y * 32, c0 = blockIdx.x * 32;
    int tx = threadIdx.x, ty = threadIdx.y;  // 32 x 8
#pragma unroll
    for (int i = 0; i < 32; i += 8)
        tle[ty + i][tx] = M[(size_t)(k0 + ty + i) * DD + c0 + tx];
    __syncthreads();
#pragma unroll
    for (int i = 0; i < 32; i += 8)
        MT[(size_t)(c0 + ty + i) * DD + k0 + tx] = f2bf(tle[tx][ty + i]);
}

// f32 64x64-tile GEMM accumulate core (256 threads)
__device__ __forceinline__ void gemm_acc64(const float* __restrict__ Ab,
                                           const float* __restrict__ Bb,
                                           int lda, int ldb,
                                           int rowBase, int colBase,
                                           float acc[4][4]) {
    __shared__ __align__(16) float As[16][68];
    __shared__ __align__(16) float Bs[16][68];
    const int tid = threadIdx.x;
    const int tx = tid & 15, ty = tid >> 4;
    const int a_m = tid >> 2;
    const int a_k = (tid & 3) << 2;
    const int b_k = tid >> 4;
    const int b_n = (tid & 15) << 2;

#pragma unroll
    for (int i = 0; i < 4; ++i)
#pragma unroll
        for (int j = 0; j < 4; ++j) acc[i][j] = 0.0f;

    for (int k0 = 0; k0 < DD; k0 += 16) {
        float4 av = *(const float4*)(Ab + (size_t)(rowBase + a_m) * lda + (k0 + a_k));
        As[a_k + 0][a_m] = av.x;
        As[a_k + 1][a_m] = av.y;
        As[a_k + 2][a_m] = av.z;
        As[a_k + 3][a_m] = av.w;
        *(float4*)(&Bs[b_k][b_n]) =
            *(const float4*)(Bb + (size_t)(k0 + b_k) * ldb + (colBase + b_n));
        __syncthreads();
#pragma unroll
        for (int kk = 0; kk < 16; ++kk) {
            float a4[4], b4[4];
            *(float4*)a4 = *(const float4*)(&As[kk][ty << 2]);
            *(float4*)b4 = *(const float4*)(&Bs[kk][tx << 2]);
#pragma unroll
            for (int i = 0; i < 4; ++i)
#pragma unroll
                for (int j = 0; j < 4; ++j)
                    acc[i][j] += a4[i] * b4[j];
        }
        __syncthreads();
    }
}

// Batched 256^3 f32 GEMM. epi: 0->C=acc ; 1->C=acc+I ; 2->C=2*acc+I
__global__ void gemm256_kernel(const float* __restrict__ A, const float* __restrict__ Bm,
                               float* __restrict__ C,
                               int lda, int ldb, int ldc,
                               long long sA, long long sB, long long sC, int epi) {
    float acc[4][4];
    const int rowBase = blockIdx.y * 64, colBase = blockIdx.x * 64;
    gemm_acc64(A + blockIdx.z * sA, Bm + blockIdx.z * sB, lda, ldb, rowBase, colBase, acc);
    float* Cb = C + blockIdx.z * sC;
    const int tid = threadIdx.x;
    const int tx = tid & 15, ty = tid >> 4;
    const int c0 = colBase + (tx << 2);
#pragma unroll
    for (int i = 0; i < 4; ++i) {
        int r = rowBase + (ty << 2) + i;
        float4 v;
        float* vp = (float*)&v;
#pragma unroll
        for (int j = 0; j < 4; ++j) {
            float x = acc[i][j];
            if (epi == 1) x += (r == c0 + j) ? 1.0f : 0.0f;
            else if (epi == 2) x = 2.0f * x + ((r == c0 + j) ? 1.0f : 0.0f);
            vp[j] = x;
        }
        *(float4*)(Cb + (size_t)r * ldc + c0) = v;
    }
}

// Checkpoints (batched): Z_i = z0 @ W_i -> f32 to out[:,32i-1,:], bf16 to Zb[i] (i<16)
__global__ void chk_kernel(const float* __restrict__ z0, const float* __restrict__ Wtab,
                           float* __restrict__ out, unsigned short* __restrict__ Zb) {
    const int i = blockIdx.z + 1;  // 1..16
    float acc[4][4];
    const int rowBase = blockIdx.y * 64, colBase = blockIdx.x * 64;
    gemm_acc64(z0, Wtab + (size_t)blockIdx.z * MATF, DD, DD, rowBase, colBase, acc);
    const int tid = threadIdx.x;
    const int tx = tid & 15, ty = tid >> 4;
    const int c0 = colBase + (tx << 2);
    float* Of = out + (size_t)(32 * i - 1) * DD;
    unsigned short* Zo = (i < 16) ? (Zb + (size_t)i * MATF) : (unsigned short*)0;
#pragma unroll
    for (int ii = 0; ii < 4; ++ii) {
        int r = rowBase + (ty << 2) + ii;
        float4 v;
        float* vp = (float*)&v;
#pragma unroll
        for (int jj = 0; jj < 4; ++jj) vp[jj] = acc[ii][jj];
        *(float4*)(Of + (size_t)r * (TT * DD) + c0) = v;
        if (Zo) {
            unsigned int w0 = (unsigned int)f2bf(vp[0]) | ((unsigned int)f2bf(vp[1]) << 16);
            unsigned int w1 = (unsigned int)f2bf(vp[2]) | ((unsigned int)f2bf(vp[3]) << 16);
            uint2 w;
            w.x = w0;
            w.y = w1;
            *(uint2*)(Zo + (size_t)r * DD + c0) = w;
        }
    }
}

// Batched bf16 MFMA fill: out[:, i*32+j-1, :] = Zb[i] @ M_j  (i=0..15, j=1..31)
// 128x128 tile, 4 waves, XOR-swizzled LDS, mfma_f32_16x16x32_bf16.
__global__ void __launch_bounds__(256)
fill_kernel(const unsigned short* __restrict__ Zb,
            const unsigned short* __restrict__ MTb,
            float* __restrict__ out) {
    __shared__ __align__(16) unsigned short As[128 * 64];
    __shared__ __align__(16) unsigned short Bs[128 * 64];
    const int bz = blockIdx.z;
    const int i = bz / 31;
    const int j = bz % 31 + 1;
    const int t = i * 32 + j - 1;
    const unsigned short* Zt = Zb + (size_t)i * MATF;   // [row][k]
    const unsigned short* MT = MTb + (size_t)(j - 1) * MATF;  // [col][k]
    float* C = out + (size_t)t * DD;  // row stride TT*DD

    const int tid = threadIdx.x;
    const int lane = tid & 63, wid = tid >> 6;
    const int rowBase = blockIdx.y * 128, colBase = blockIdx.x * 128;
    const int wr = (wid >> 1) * 64, wc = (wid & 1) * 64;

    char* asb = (char*)As;
    char* bsb = (char*)Bs;

    f32x4 acc[4][4];
#pragma unroll
    for (int a = 0; a < 4; ++a)
#pragma unroll
        for (int b = 0; b < 4; ++b) acc[a][b] = (f32x4){0.f, 0.f, 0.f, 0.f};

    for (int k0 = 0; k0 < DD; k0 += 64) {
#pragma unroll
        for (int q = 0; q < 4; ++q) {
            int chunk = q * 256 + tid;
            int row = chunk >> 3;          // 0..127
            int kc = (chunk & 7) << 3;     // 0..56
            int off = (row * 128 + kc * 2) ^ ((row & 7) << 4);
            int4 va = *(const int4*)(Zt + (size_t)(rowBase + row) * DD + k0 + kc);
            *(int4*)(asb + off) = va;
            int4 vb = *(const int4*)(MT + (size_t)(colBase + row) * DD + k0 + kc);
            *(int4*)(bsb + off) = vb;
        }
        __syncthreads();
#pragma unroll
        for (int ks = 0; ks < 2; ++ks) {
            bf16x8 af[4], bg[4];
            const int kk = ks * 32 + (lane >> 4) * 8;
#pragma unroll
            for (int f = 0; f < 4; ++f) {
                int r = wr + f * 16 + (lane & 15);
                af[f] = *(const bf16x8*)(asb + ((r * 128 + kk * 2) ^ ((r & 7) << 4)));
                int c = wc + f * 16 + (lane & 15);
                bg[f] = *(const bf16x8*)(bsb + ((c * 128 + kk * 2) ^ ((c & 7) << 4)));
            }
#pragma unroll
            for (int fr = 0; fr < 4; ++fr)
#pragma unroll
                for (int fc = 0; fc < 4; ++fc)
                    acc[fr][fc] = __builtin_amdgcn_mfma_f32_16x16x32_bf16(
                        af[fr], bg[fc], acc[fr][fc], 0, 0, 0);
        }
        __syncthreads();
    }

#pragma unroll
    for (int fr = 0; fr < 4; ++fr) {
        int r0 = rowBase + wr + fr * 16 + (lane >> 4) * 4;
#pragma unroll
        for (int fc = 0; fc < 4; ++fc) {
            int c = colBase + wc + fc * 16 + (lane & 15);
#pragma unroll
            for (int ii = 0; ii < 4; ++ii)
                C[(size_t)(r0 + ii) * (TT * DD) + c] = acc[fr][fc][ii];
        }
    }
}

// f32 fallback fill (round-1 path): out[:, i*J+j-1, :] = Z_i @ M_j
__global__ void stage3_kernel(const float* __restrict__ z0, const float* __restrict__ Mtab,
                              float* __restrict__ out, int J) {
    int bz = blockIdx.z;
    int i = bz / (J - 1);
    int j = bz % (J - 1) + 1;
    const float* Ab;
    int lda;
    if (i == 0) { Ab = z0; lda = DD; }
    else { Ab = out + (size_t)(i * J - 1) * DD; lda = TT * DD; }
    float acc[4][4];
    const int rowBase = blockIdx.y * 64, colBase = blockIdx.x * 64;
    gemm_acc64(Ab, Mtab + (size_t)(j - 1) * MATF, lda, DD, rowBase, colBase, acc);
    float* Cb = out + (size_t)(i * J + j - 1) * DD;
    const int tid = threadIdx.x;
    const int tx = tid & 15, ty = tid >> 4;
    const int c0 = colBase + (tx << 2);
#pragma unroll
    for (int ii = 0; ii < 4; ++ii) {
        int r = rowBase + (ty << 2) + ii;
        float4 v;
        float* vp = (float*)&v;
#pragma unroll
        for (int jj = 0; jj < 4; ++jj) vp[jj] = acc[ii][jj];
        *(float4*)(Cb + (size_t)r * (TT * DD) + c0) = v;
    }
}

extern "C" void kernel_launch(void* const* d_in, const int* in_sizes, int n_in,
                              void* d_out, int out_size, void* d_ws, size_t ws_size,
                              hipStream_t stream) {
    const float* z0 = (const float*)d_in[0];
    const float* Kmat = (const float*)d_in[1];
    const float* log_dt = (const float*)d_in[2];
    float* out = (float*)d_out;

    dim3 blk(256);
    dim3 g1(4, 4, 1);

    // Tier A: A|Xa|Xb|Mtab[32]|Wtab[16] f32  +  MTb[31]|Zb[16] bf16
    const size_t needA = (size_t)(3 + 32 + 16) * MATF * 4 + (size_t)(31 + 16) * MATF * 2;
    if (ws_size >= needA) {
        float* Amat = (float*)d_ws;
        float* Xa = Amat + MATF;
        float* Xb = Xa + MATF;
        float* Mtab = Xb + MATF;
        float* Wtab = Mtab + (size_t)32 * MATF;
        unsigned short* MTb = (unsigned short*)(Wtab + (size_t)16 * MATF);
        unsigned short* Zb = MTb + (size_t)31 * MATF;

        prep_kernel<<<MATF / 256, blk, 0, stream>>>(Kmat, log_dt, z0, Amat, Xa, Zb);

        // Neumann/Horner: 2 iters + final => Kd = I+2A+2A^2+2A^3+2A^4 (err ~2e-10)
        gemm256_kernel<<<g1, blk, 0, stream>>>(Amat, Xa, Xb, DD, DD, DD, 0, 0, 0, 1);
        gemm256_kernel<<<g1, blk, 0, stream>>>(Amat, Xb, Xa, DD, DD, DD, 0, 0, 0, 1);
        gemm256_kernel<<<g1, blk, 0, stream>>>(Amat, Xa, Mtab, DD, DD, DD, 0, 0, 0, 2);

        // M powers: M_{p+q} = M_q @ M_p (log depth) -> M_1..M_32
        for (int p = 1; p < 32; p <<= 1)
            gemm256_kernel<<<dim3(4, 4, p), blk, 0, stream>>>(
                Mtab, Mtab + (size_t)(p - 1) * MATF, Mtab + (size_t)p * MATF,
                DD, DD, DD, MATF, 0, MATF, 0);

        // W powers: W_1 = Kd^32 ; W_{p+q} = W_q @ W_p -> W_1..W_16
        copyw_kernel<<<MATF / 4 / 256, blk, 0, stream>>>(Mtab + (size_t)31 * MATF, Wtab);
        for (int p = 1; p < 16; p <<= 1)
            gemm256_kernel<<<dim3(4, 4, p), blk, 0, stream>>>(
                Wtab, Wtab + (size_t)(p - 1) * MATF, Wtab + (size_t)p * MATF,
                DD, DD, DD, MATF, 0, MATF, 0);

        // bf16 transposed M table (runs independent of W powers)
        mtrans_kernel<<<dim3(8, 8, 31), dim3(32, 8), 0, stream>>>(Mtab, MTb);

        // All 16 checkpoints in one batched launch
        chk_kernel<<<dim3(4, 4, 16), blk, 0, stream>>>(z0, Wtab, out, Zb);

        // All 496 remaining timesteps in one batched MFMA launch
        fill_kernel<<<dim3(2, 2, 496), blk, 0, stream>>>(Zb, MTb, out);
        return;
    }

    // Tier B fallback (round-1 proven path, f32 throughout)
    int J = 32;
    while (J > 4 && (size_t)(3 + J) * MATF * sizeof(float) > ws_size) J >>= 1;
    float* Amat = (float*)d_ws;
    float* Xa = Amat + MATF;
    float* Xb = Xa + MATF;
    float* Mtab = Xb + MATF;

    prep_kernel<<<MATF / 256, blk, 0, stream>>>(Kmat, log_dt, z0, Amat, Xa,
                                                (unsigned short*)0);
    gemm256_kernel<<<g1, blk, 0, stream>>>(Amat, Xa, Xb, DD, DD, DD, 0, 0, 0, 1);
    gemm256_kernel<<<g1, blk, 0, stream>>>(Amat, Xb, Xa, DD, DD, DD, 0, 0, 0, 1);
    gemm256_kernel<<<g1, blk, 0, stream>>>(Amat, Xa, Mtab, DD, DD, DD, 0, 0, 0, 2);
    for (int p = 1; p < J; p <<= 1)
        gemm256_kernel<<<dim3(4, 4, p), blk, 0, stream>>>(
            Mtab, Mtab + (size_t)(p - 1) * MATF, Mtab + (size_t)p * MATF,
            DD, DD, DD, MATF, 0, MATF, 0);
    const float* W = Mtab + (size_t)(J - 1) * MATF;
    const int nChain = TT / J;
    for (int i = 1; i <= nChain; ++i) {
        const float* Ain = (i == 1) ? z0 : out + (size_t)((i - 1) * J - 1) * DD;
        int lda = (i == 1) ? DD : TT * DD;
        gemm256_kernel<<<g1, blk, 0, stream>>>(Ain, W, out + (size_t)(i * J - 1) * DD,
                                               lda, DD, TT * DD, 0, 0, 0, 0);
    }
    stage3_kernel<<<dim3(4, 4, nChain * (J - 1)), blk, 0, stream>>>(z0, Mtab, out, J);
}

// Round 3
// 161.256 us; speedup vs baseline: 3.7151x; 1.5501x over previous
//
#include <hip/hip_runtime.h>

// Koopman bilinear rollout: preds[b,t,d] = (z0 @ Kd^{t+1})[b,d], D=B=256, T=512.
// Kd = (I-A)^-1(I+A), A=0.5*dt*K, ||A||~0.01 -> order-4 Neumann (2 launches).
// Parallel-in-time: M_j=Kd^j (j=1..32, log-depth), W_i=Kd^{32i} (i=1..16,
// log-depth, W_1 aliases M_32), 16 checkpoints in one batched launch, 496
// remaining timesteps in one batched bf16-MFMA launch.
// Small 256^3 GEMMs use 32x32 tiles (64 blocks) + register prefetch to cut
// the latency-bound stage time (~12us -> ~2us each).

#define DD 256
#define TT 512
#define MATF (DD * DD)

typedef __attribute__((ext_vector_type(8))) short bf16x8;
typedef __attribute__((ext_vector_type(4))) float f32x4;

static __device__ __forceinline__ unsigned short f2bf(float f) {
    unsigned int u = __float_as_uint(f);
    u += 0x7fffu + ((u >> 16) & 1u);
    return (unsigned short)(u >> 16);
}

// A = 0.5*exp(log_dt)*K ; Zb0 = bf16(z0)
__global__ void prep_kernel(const float* __restrict__ K,
                            const float* __restrict__ log_dt,
                            const float* __restrict__ z0,
                            float* __restrict__ A,
                            unsigned short* __restrict__ Zb0) {
    int idx = blockIdx.x * blockDim.x + threadIdx.x;
    float c = 0.5f * expf(log_dt[0]);
    A[idx] = c * K[idx];
    if (Zb0) Zb0[idx] = f2bf(z0[idx]);
}

// MTb_j[c][k] = bf16(M_j[k][c])  (transpose+convert, 32x32 LDS tiles)
__global__ void mtrans_kernel(const float* __restrict__ Mtab,
                              unsigned short* __restrict__ MTb) {
    __shared__ float tle[32][33];
    int j = blockIdx.z;
    const float* M = Mtab + (size_t)j * MATF;
    unsigned short* MT = MTb + (size_t)j * MATF;
    int k0 = blockIdx.y * 32, c0 = blockIdx.x * 32;
    int tx = threadIdx.x, ty = threadIdx.y;  // 32 x 8
#pragma unroll
    for (int i = 0; i < 32; i += 8)
        tle[ty + i][tx] = M[(size_t)(k0 + ty + i) * DD + c0 + tx];
    __syncthreads();
#pragma unroll
    for (int i = 0; i < 32; i += 8)
        MT[(size_t)(c0 + ty + i) * DD + k0 + tx] = f2bf(tle[tx][ty + i]);
}

// ---- 32x32-tile f32 GEMM core: 256 threads, K=256, K_BLK=64, reg prefetch ----
// As stored [k][m] pad 38; Bs stored [k][n] pad 40 (b64/b128 alignment kept).
__device__ __forceinline__ void g32_core(const float* __restrict__ Ab, int lda,
                                         const float* __restrict__ Bb, int ldb,
                                         int rowBase, int colBase, float acc[2][2]) {
    __shared__ __align__(16) float As[64 * 38];
    __shared__ __align__(16) float Bs[64 * 40];
    const int tid = threadIdx.x;
    const int tx = tid & 15, ty = tid >> 4;
    const int am = tid >> 4;         // 0..15 (A tile row, +16 for 2nd slot)
    const int ak = (tid & 15) << 2;  // 0..60 (k within K_BLK)
    const int bk = tid >> 3;         // 0..31 (B tile k, +32 for 2nd slot)
    const int bn = (tid & 7) << 2;   // 0..28

    acc[0][0] = acc[0][1] = acc[1][0] = acc[1][1] = 0.f;

    float4 pa0 = *(const float4*)(Ab + (size_t)(rowBase + am) * lda + ak);
    float4 pa1 = *(const float4*)(Ab + (size_t)(rowBase + am + 16) * lda + ak);
    float4 pb0 = *(const float4*)(Bb + (size_t)bk * ldb + colBase + bn);
    float4 pb1 = *(const float4*)(Bb + (size_t)(bk + 32) * ldb + colBase + bn);

    for (int k0 = 0; k0 < DD; k0 += 64) {
        As[(ak + 0) * 38 + am] = pa0.x;
        As[(ak + 1) * 38 + am] = pa0.y;
        As[(ak + 2) * 38 + am] = pa0.z;
        As[(ak + 3) * 38 + am] = pa0.w;
        As[(ak + 0) * 38 + am + 16] = pa1.x;
        As[(ak + 1) * 38 + am + 16] = pa1.y;
        As[(ak + 2) * 38 + am + 16] = pa1.z;
        As[(ak + 3) * 38 + am + 16] = pa1.w;
        *(float4*)(&Bs[bk * 40 + bn]) = pb0;
        *(float4*)(&Bs[(bk + 32) * 40 + bn]) = pb1;
        __syncthreads();
        if (k0 + 64 < DD) {  // prefetch next round while computing this one
            pa0 = *(const float4*)(Ab + (size_t)(rowBase + am) * lda + k0 + 64 + ak);
            pa1 = *(const float4*)(Ab + (size_t)(rowBase + am + 16) * lda + k0 + 64 + ak);
            pb0 = *(const float4*)(Bb + (size_t)(bk + k0 + 64) * ldb + colBase + bn);
            pb1 = *(const float4*)(Bb + (size_t)(bk + 32 + k0 + 64) * ldb + colBase + bn);
        }
#pragma unroll
        for (int kk = 0; kk < 64; ++kk) {
            float2 a2 = *(const float2*)(&As[kk * 38 + (ty << 1)]);
            float2 b2 = *(const float2*)(&Bs[kk * 40 + (tx << 1)]);
            acc[0][0] = fmaf(a2.x, b2.x, acc[0][0]);
            acc[0][1] = fmaf(a2.x, b2.y, acc[0][1]);
            acc[1][0] = fmaf(a2.y, b2.x, acc[1][0]);
            acc[1][1] = fmaf(a2.y, b2.y, acc[1][1]);
        }
        __syncthreads();
    }
}

// EPI 0: C = acc
// EPI 1: C = acc (=A@A) ; C2 = 2I + 2E + 2acc   (Neumann stage 1, E = A)
// EPI 2: C = acc + I + 2E                        (Neumann stage 2, E = A)
template <int EPI>
__global__ void __launch_bounds__(256)
g32_kernel(const float* __restrict__ A, const float* __restrict__ B,
           float* __restrict__ C, const float* __restrict__ E,
           float* __restrict__ C2,
           int lda, int ldb, int ldc,
           long long sA, long long sB, long long sC) {
    float acc[2][2];
    const int rowBase = blockIdx.y << 5, colBase = blockIdx.x << 5;
    g32_core(A + blockIdx.z * sA, lda, B + blockIdx.z * sB, ldb, rowBase, colBase, acc);
    float* Cb = C + blockIdx.z * sC;
    const int r0 = rowBase + ((threadIdx.x >> 4) << 1);
    const int c0 = colBase + ((threadIdx.x & 15) << 1);
#pragma unroll
    for (int i = 0; i < 2; ++i) {
        int r = r0 + i;
        float2 v;
        if (EPI == 2) {
            float e0 = E[(size_t)r * DD + c0], e1 = E[(size_t)r * DD + c0 + 1];
            v.x = acc[i][0] + 2.f * e0 + (r == c0 ? 1.f : 0.f);
            v.y = acc[i][1] + 2.f * e1 + (r == c0 + 1 ? 1.f : 0.f);
        } else {
            v.x = acc[i][0];
            v.y = acc[i][1];
        }
        *(float2*)(Cb + (size_t)r * ldc + c0) = v;
        if (EPI == 1) {
            float e0 = E[(size_t)r * DD + c0], e1 = E[(size_t)r * DD + c0 + 1];
            float2 w;
            w.x = 2.f * acc[i][0] + 2.f * e0 + (r == c0 ? 2.f : 0.f);
            w.y = 2.f * acc[i][1] + 2.f * e1 + (r == c0 + 1 ? 2.f : 0.f);
            *(float2*)(C2 + (size_t)r * DD + c0) = w;
        }
    }
}

// Checkpoints (batched, 32x32 tiles): Z_i = z0 @ W_i -> f32 out[:,32i-1,:],
// bf16 to Zb[i] for i<16.
__global__ void __launch_bounds__(256)
chk32_kernel(const float* __restrict__ z0, const float* __restrict__ Wbase,
             float* __restrict__ out, unsigned short* __restrict__ Zb) {
    const int i = blockIdx.z + 1;  // 1..16
    float acc[2][2];
    const int rowBase = blockIdx.y << 5, colBase = blockIdx.x << 5;
    g32_core(z0, DD, Wbase + (size_t)blockIdx.z * MATF, DD, rowBase, colBase, acc);
    const int r0 = rowBase + ((threadIdx.x >> 4) << 1);
    const int c0 = colBase + ((threadIdx.x & 15) << 1);
    float* Of = out + (size_t)(32 * i - 1) * DD;
    unsigned short* Zo = (i < 16) ? Zb + (size_t)i * MATF : (unsigned short*)0;
#pragma unroll
    for (int ii = 0; ii < 2; ++ii) {
        int r = r0 + ii;
        float2 v;
        v.x = acc[ii][0];
        v.y = acc[ii][1];
        *(float2*)(Of + (size_t)r * (TT * DD) + c0) = v;
        if (Zo) {
            unsigned int w = (unsigned int)f2bf(v.x) | ((unsigned int)f2bf(v.y) << 16);
            *(unsigned int*)(Zo + (size_t)r * DD + c0) = w;
        }
    }
}

// Batched bf16 MFMA fill: out[:, i*32+j-1, :] = Zb[i] @ M_j  (i=0..15, j=1..31)
// 128x128 tile, 4 waves, XOR-swizzled LDS, mfma_f32_16x16x32_bf16. (proven r2)
__global__ void __launch_bounds__(256)
fill_kernel(const unsigned short* __restrict__ Zb,
            const unsigned short* __restrict__ MTb,
            float* __restrict__ out) {
    __shared__ __align__(16) unsigned short As[128 * 64];
    __shared__ __align__(16) unsigned short Bs[128 * 64];
    const int bz = blockIdx.z;
    const int i = bz / 31;
    const int j = bz % 31 + 1;
    const int t = i * 32 + j - 1;
    const unsigned short* Zt = Zb + (size_t)i * MATF;         // [row][k]
    const unsigned short* MT = MTb + (size_t)(j - 1) * MATF;  // [col][k]
    float* C = out + (size_t)t * DD;                          // row stride TT*DD

    const int tid = threadIdx.x;
    const int lane = tid & 63, wid = tid >> 6;
    const int rowBase = blockIdx.y * 128, colBase = blockIdx.x * 128;
    const int wr = (wid >> 1) * 64, wc = (wid & 1) * 64;

    char* asb = (char*)As;
    char* bsb = (char*)Bs;

    f32x4 acc[4][4];
#pragma unroll
    for (int a = 0; a < 4; ++a)
#pragma unroll
        for (int b = 0; b < 4; ++b) acc[a][b] = (f32x4){0.f, 0.f, 0.f, 0.f};

    for (int k0 = 0; k0 < DD; k0 += 64) {
#pragma unroll
        for (int q = 0; q < 4; ++q) {
            int chunk = q * 256 + tid;
            int row = chunk >> 3;       // 0..127
            int kc = (chunk & 7) << 3;  // 0..56
            int off = (row * 128 + kc * 2) ^ ((row & 7) << 4);
            int4 va = *(const int4*)(Zt + (size_t)(rowBase + row) * DD + k0 + kc);
            *(int4*)(asb + off) = va;
            int4 vb = *(const int4*)(MT + (size_t)(colBase + row) * DD + k0 + kc);
            *(int4*)(bsb + off) = vb;
        }
        __syncthreads();
#pragma unroll
        for (int ks = 0; ks < 2; ++ks) {
            bf16x8 af[4], bg[4];
            const int kk = ks * 32 + (lane >> 4) * 8;
#pragma unroll
            for (int f = 0; f < 4; ++f) {
                int r = wr + f * 16 + (lane & 15);
                af[f] = *(const bf16x8*)(asb + ((r * 128 + kk * 2) ^ ((r & 7) << 4)));
                int c = wc + f * 16 + (lane & 15);
                bg[f] = *(const bf16x8*)(bsb + ((c * 128 + kk * 2) ^ ((c & 7) << 4)));
            }
#pragma unroll
            for (int fr = 0; fr < 4; ++fr)
#pragma unroll
                for (int fc = 0; fc < 4; ++fc)
                    acc[fr][fc] = __builtin_amdgcn_mfma_f32_16x16x32_bf16(
                        af[fr], bg[fc], acc[fr][fc], 0, 0, 0);
        }
        __syncthreads();
    }

#pragma unroll
    for (int fr = 0; fr < 4; ++fr) {
        int r0 = rowBase + wr + fr * 16 + (lane >> 4) * 4;
#pragma unroll
        for (int fc = 0; fc < 4; ++fc) {
            int c = colBase + wc + fc * 16 + (lane & 15);
#pragma unroll
            for (int ii = 0; ii < 4; ++ii)
                C[(size_t)(r0 + ii) * (TT * DD) + c] = acc[fr][fc][ii];
        }
    }
}

extern "C" void kernel_launch(void* const* d_in, const int* in_sizes, int n_in,
                              void* d_out, int out_size, void* d_ws, size_t ws_size,
                              hipStream_t stream) {
    const float* z0 = (const float*)d_in[0];
    const float* Kmat = (const float*)d_in[1];
    const float* log_dt = (const float*)d_in[2];
    float* out = (float*)d_out;

    dim3 blk(256);

    // ws layout: A | A2 | Bop | Mtab[47] (M_1..M_32, W_2..W_16; W_1 = M_32)
    //            | MTb[31] bf16 | Zb[16] bf16
    float* A = (float*)d_ws;
    float* A2 = A + MATF;
    float* Bop = A2 + MATF;
    float* Mtab = Bop + MATF;
    unsigned short* MTb = (unsigned short*)(Mtab + (size_t)47 * MATF);
    unsigned short* Zb = MTb + (size_t)31 * MATF;
    const size_t needA =
        (size_t)(3 + 47) * MATF * sizeof(float) + (size_t)(31 + 16) * MATF * 2;

    if (ws_size >= needA) {
        prep_kernel<<<MATF / 256, blk, 0, stream>>>(Kmat, log_dt, z0, A, Zb);

        dim3 g(8, 8, 1);
        // Neumann (order 4) in 2 GEMMs: A2 = A@A (+Bop epi); Kd = A2@Bop + I + 2A
        g32_kernel<1><<<g, blk, 0, stream>>>(A, A, A2, A, Bop, DD, DD, DD, 0, 0, 0);
        g32_kernel<2><<<g, blk, 0, stream>>>(A2, Bop, Mtab, A, (float*)0,
                                             DD, DD, DD, 0, 0, 0);

        // M powers: M_{q+p} = M_q @ M_p (log depth) -> M_1..M_32
        for (int p = 1; p < 32; p <<= 1)
            g32_kernel<0><<<dim3(8, 8, p), blk, 0, stream>>>(
                Mtab, Mtab + (size_t)(p - 1) * MATF, Mtab + (size_t)p * MATF,
                (const float*)0, (float*)0, DD, DD, DD, MATF, 0, MATF);

        // W powers: W_1 = M_32 (aliased); W_{q+p} = W_q @ W_p -> W_1..W_16
        float* Wb = Mtab + (size_t)31 * MATF;
        for (int p = 1; p < 16; p <<= 1)
            g32_kernel<0><<<dim3(8, 8, p), blk, 0, stream>>>(
                Wb, Wb + (size_t)(p - 1) * MATF, Wb + (size_t)p * MATF,
                (const float*)0, (float*)0, DD, DD, DD, MATF, 0, MATF);

        // bf16 transposed M table
        mtrans_kernel<<<dim3(8, 8, 31), dim3(32, 8), 0, stream>>>(Mtab, MTb);

        // All 16 checkpoints in one batched launch
        chk32_kernel<<<dim3(8, 8, 16), blk, 0, stream>>>(z0, Wb, out, Zb);

        // All 496 remaining timesteps in one batched MFMA launch
        fill_kernel<<<dim3(2, 2, 496), blk, 0, stream>>>(Zb, MTb, out);
        return;
    }

    // Minimal fallback (tiny ws): Kd in 4 matrices, then 512 chained GEMMs.
    float* Kd = Bop + MATF;
    prep_kernel<<<MATF / 256, blk, 0, stream>>>(Kmat, log_dt, z0, A,
                                                (unsigned short*)0);
    dim3 g(8, 8, 1);
    g32_kernel<1><<<g, blk, 0, stream>>>(A, A, A2, A, Bop, DD, DD, DD, 0, 0, 0);
    g32_kernel<2><<<g, blk, 0, stream>>>(A2, Bop, Kd, A, (float*)0, DD, DD, DD, 0, 0, 0);
    for (int t = 0; t < TT; ++t) {
        const float* Ain = (t == 0) ? z0 : out + (size_t)(t - 1) * DD;
        int lda = (t == 0) ? DD : TT * DD;
        g32_kernel<0><<<g, blk, 0, stream>>>(Ain, Kd, out + (size_t)t * DD,
                                             (const float*)0, (float*)0,
                                             lda, DD, TT * DD, 0, 0, 0);
    }
}